// Round 9
// baseline (276.577 us; speedup 1.0000x reference)
//
#include <hip/hip_runtime.h>
#include <hip/hip_bf16.h>

#define N 8192
#define Dd 128

typedef short short8 __attribute__((ext_vector_type(8)));
typedef float floatx4 __attribute__((ext_vector_type(4)));

// round-to-nearest-even fp32 -> bf16 (no NaN in inputs)
static __device__ inline unsigned short f2bf(float f) {
    unsigned int u = __float_as_uint(f);
    return (unsigned short)((u + 0x7fffu + ((u >> 16) & 1u)) >> 16);
}
static __device__ inline float bf2f(unsigned short b) {
    return __uint_as_float(((unsigned int)b) << 16);
}

// One wave per row: convert to bf16, store, and compute row norm of the
// *rounded* values so the gram diagonal cancels exactly.
__global__ __launch_bounds__(256) void prep_kernel(const float* __restrict__ z,
                                                   unsigned short* __restrict__ zb,
                                                   float* __restrict__ sq) {
    int row  = blockIdx.x * 4 + (threadIdx.x >> 6);
    int lane = threadIdx.x & 63;
    float2 v = ((const float2*)z)[row * 64 + lane];
    unsigned short b0 = f2bf(v.x);
    unsigned short b1 = f2bf(v.y);
    float f0 = bf2f(b0), f1 = bf2f(b1);
    ushort2 st; st.x = b0; st.y = b1;
    ((ushort2*)zb)[row * 64 + lane] = st;
    float s = f0 * f0 + f1 * f1;
    #pragma unroll
    for (int off = 32; off > 0; off >>= 1) s += __shfl_down(s, off, 64);
    if (lane == 0) sq[row] = s;
}

// SYMMETRY EXPLOIT: out is symmetric and tile (by,bx) is bit-identical to
// tile (bx,by)^T (same dot products, same K order -- R8 passed with
// absmax 0.0 storing transposed). So only upper-triangle blocks run
// (2080 of 4096); each stores its tile twice: normal (R1 scattered-dword,
// best-measured pattern) + mirrored-transposed (R8 float4, free-wide under
// transpose). HBM writes unchanged (256 MB) but MFMA/LDS/L2/exp work all
// HALVE -> the store stream's duty cycle across resident blocks rises.
// (R1..R8 established: store pattern, blocks/CU, XCD swizzle, intra-block
// waves are all non-levers; phase duty cycle is the remaining theory.)
__global__ __launch_bounds__(256, 2) void pairsim_kernel(const unsigned short* __restrict__ zb,
                                                         const float* __restrict__ sq,
                                                         float* __restrict__ out) {
    __shared__ unsigned short lA[128 * 128];
    __shared__ unsigned short lB[128 * 128];

    int bx = blockIdx.x, by = blockIdx.y;
    if (by > bx) return;                      // lower triangle: no-op
    int colBase = bx * 128, rowBase = by * 128;
    int t  = threadIdx.x;
    int r0 = t >> 4, cg = t & 15;   // 16 rows x 16 chunks per pass, 8 passes

    const uint4* gA = (const uint4*)(zb + (size_t)rowBase * Dd);
    const uint4* gB = (const uint4*)(zb + (size_t)colBase * Dd);
    uint4 va[8], vb[8];
    #pragma unroll
    for (int i = 0; i < 8; i++) va[i] = gA[(r0 + i * 16) * 16 + cg];
    #pragma unroll
    for (int i = 0; i < 8; i++) vb[i] = gB[(r0 + i * 16) * 16 + cg];

    int scg = ((cg ^ r0) * 8);      // swizzled chunk offset (elements)
    #pragma unroll
    for (int i = 0; i < 8; i++) *(uint4*)&lA[(r0 + i * 16) * 128 + scg] = va[i];
    #pragma unroll
    for (int i = 0; i < 8; i++) *(uint4*)&lB[(r0 + i * 16) * 128 + scg] = vb[i];
    __syncthreads();

    int w = t >> 6, lane = t & 63;
    int wr = (w >> 1) * 64, wc = (w & 1) * 64;   // 2x2 waves -> 64x64 each
    int m = lane & 15, quad = lane >> 4;

    floatx4 zero = {0.f, 0.f, 0.f, 0.f};
    floatx4 acc[4][4];
    #pragma unroll
    for (int i = 0; i < 4; i++)
        #pragma unroll
        for (int j = 0; j < 4; j++) acc[i][j] = zero;

    #pragma unroll
    for (int ks = 0; ks < 4; ks++) {
        short8 af[4], bfr[4];
        int c = ks * 4 + quad;      // 16B chunk index along K
        #pragma unroll
        for (int i = 0; i < 4; i++)
            af[i] = *(const short8*)&lA[(wr + i * 16 + m) * 128 + ((c ^ m) * 8)];
        #pragma unroll
        for (int j = 0; j < 4; j++)
            bfr[j] = *(const short8*)&lB[(wc + j * 16 + m) * 128 + ((c ^ m) * 8)];
        #pragma unroll
        for (int i = 0; i < 4; i++)
            #pragma unroll
            for (int j = 0; j < 4; j++)
                acc[i][j] = __builtin_amdgcn_mfma_f32_16x16x32_bf16(af[i], bfr[j], acc[i][j], 0, 0, 0);
    }

    // Epilogue: value v(row,col) = exp(-max(sq_r+sq_c-2g,0)).
    // C layout: col = lane&15 (m), row = quad*4 + reg.
    bool mirror = (by != bx);
    #pragma unroll
    for (int j = 0; j < 4; j++) {
        int col = colBase + wc + j * 16 + m;
        float sc = sq[col];
        #pragma unroll
        for (int i = 0; i < 4; i++) {
            int rowY = rowBase + wr + i * 16 + quad * 4;
            float4 srv = *(const float4*)&sq[rowY];
            float4 v;
            v.x = __expf(fminf(2.0f * acc[i][j][0] - srv.x - sc, 0.0f));
            v.y = __expf(fminf(2.0f * acc[i][j][1] - srv.y - sc, 0.0f));
            v.z = __expf(fminf(2.0f * acc[i][j][2] - srv.z - sc, 0.0f));
            v.w = __expf(fminf(2.0f * acc[i][j][3] - srv.w - sc, 0.0f));
            // normal tile: scattered dwords (R1 pattern)
            out[(size_t)(rowY + 0) * N + col] = v.x;
            out[(size_t)(rowY + 1) * N + col] = v.y;
            out[(size_t)(rowY + 2) * N + col] = v.z;
            out[(size_t)(rowY + 3) * N + col] = v.w;
            // mirrored tile: transposed float4 (R8 pattern), skip on diagonal
            if (mirror)
                *(float4*)&out[(size_t)col * N + rowY] = v;
        }
    }
}

extern "C" void kernel_launch(void* const* d_in, const int* in_sizes, int n_in,
                              void* d_out, int out_size, void* d_ws, size_t ws_size,
                              hipStream_t stream) {
    const float* z = (const float*)d_in[0];
    unsigned short* zb = (unsigned short*)d_ws;                       // 2 MB bf16 copy
    float* sqv = (float*)((char*)d_ws + (size_t)N * Dd * sizeof(unsigned short)); // 32 KB norms
    float* out = (float*)d_out;

    prep_kernel<<<N / 4, 256, 0, stream>>>(z, zb, sqv);
    pairsim_kernel<<<dim3(64, 64), 256, 0, stream>>>(zb, sqv, out);
}

// Round 10
// 264.605 us; speedup vs baseline: 1.0452x; 1.0452x over previous
//
#include <hip/hip_runtime.h>
#include <hip/hip_bf16.h>

#define N 8192
#define Dd 128

typedef short short8 __attribute__((ext_vector_type(8)));
typedef float floatx4 __attribute__((ext_vector_type(4)));

// round-to-nearest-even fp32 -> bf16 (no NaN in inputs)
static __device__ inline unsigned short f2bf(float f) {
    unsigned int u = __float_as_uint(f);
    return (unsigned short)((u + 0x7fffu + ((u >> 16) & 1u)) >> 16);
}
static __device__ inline float bf2f(unsigned short b) {
    return __uint_as_float(((unsigned int)b) << 16);
}

// One wave per row: convert to bf16, store, and compute row norm of the
// *rounded* values so the gram diagonal cancels exactly.
__global__ __launch_bounds__(256) void prep_kernel(const float* __restrict__ z,
                                                   unsigned short* __restrict__ zb,
                                                   float* __restrict__ sq) {
    int row  = blockIdx.x * 4 + (threadIdx.x >> 6);
    int lane = threadIdx.x & 63;
    float2 v = ((const float2*)z)[row * 64 + lane];
    unsigned short b0 = f2bf(v.x);
    unsigned short b1 = f2bf(v.y);
    float f0 = bf2f(b0), f1 = bf2f(b1);
    ushort2 st; st.x = b0; st.y = b1;
    ((ushort2*)zb)[row * 64 + lane] = st;
    float s = f0 * f0 + f1 * f1;
    #pragma unroll
    for (int off = 32; off > 0; off >>= 1) s += __shfl_down(s, off, 64);
    if (lane == 0) sq[row] = s;
}

// R1 structure + WAVE-PRIVATE LDS-transpose epilogue (granule theory, R9:
// halving all compute changed nothing -> purely store-bound at 2.9 TB/s vs
// fill's 6.2. All prior epilogues emit 64B half-line granules per wave
// store; fill emits full 128B lines. This epilogue re-tiles each wave's
// 64x64 quadrant through its OWN 12KB LDS region (32 rows x stride-96, two
// passes, col-XOR swizzle -> 2-way/free scatter writes, row-optimal b128
// reads; DS ops are in-order per wave so NO barrier beyond the one that
// retires the bf16 panels), then stores dwordx4 with 16 lanes x 16B =
// 256B contiguous per row-touch. Store instrs/wave: 64 -> 16.
__global__ __launch_bounds__(256, 2) void pairsim_kernel(const unsigned short* __restrict__ zb,
                                                         const float* __restrict__ sq,
                                                         float* __restrict__ out) {
    __shared__ __align__(16) unsigned char smem[65536];
    unsigned short* lA = (unsigned short*)smem;            // 32 KB bf16 panel
    unsigned short* lB = (unsigned short*)(smem + 32768);  // 32 KB bf16 panel

    int bx = blockIdx.x, by = blockIdx.y;
    int colBase = bx * 128, rowBase = by * 128;
    int t  = threadIdx.x;
    int r0 = t >> 4, cg = t & 15;   // 16 rows x 16 chunks per pass, 8 passes

    const uint4* gA = (const uint4*)(zb + (size_t)rowBase * Dd);
    const uint4* gB = (const uint4*)(zb + (size_t)colBase * Dd);
    uint4 va[8], vb[8];
    #pragma unroll
    for (int i = 0; i < 8; i++) va[i] = gA[(r0 + i * 16) * 16 + cg];
    #pragma unroll
    for (int i = 0; i < 8; i++) vb[i] = gB[(r0 + i * 16) * 16 + cg];

    int scg = ((cg ^ r0) * 8);      // swizzled chunk offset (elements)
    #pragma unroll
    for (int i = 0; i < 8; i++) *(uint4*)&lA[(r0 + i * 16) * 128 + scg] = va[i];
    #pragma unroll
    for (int i = 0; i < 8; i++) *(uint4*)&lB[(r0 + i * 16) * 128 + scg] = vb[i];
    __syncthreads();

    int w = t >> 6, lane = t & 63;
    int wr = (w >> 1) * 64, wc = (w & 1) * 64;   // 2x2 waves -> 64x64 each
    int m = lane & 15, quad = lane >> 4;

    floatx4 zero = {0.f, 0.f, 0.f, 0.f};
    floatx4 acc[4][4];
    #pragma unroll
    for (int i = 0; i < 4; i++)
        #pragma unroll
        for (int j = 0; j < 4; j++) acc[i][j] = zero;

    #pragma unroll
    for (int ks = 0; ks < 4; ks++) {
        short8 af[4], bfr[4];
        int c = ks * 4 + quad;      // 16B chunk index along K
        #pragma unroll
        for (int i = 0; i < 4; i++)
            af[i] = *(const short8*)&lA[(wr + i * 16 + m) * 128 + ((c ^ m) * 8)];
        #pragma unroll
        for (int j = 0; j < 4; j++)
            bfr[j] = *(const short8*)&lB[(wc + j * 16 + m) * 128 + ((c ^ m) * 8)];
        #pragma unroll
        for (int i = 0; i < 4; i++)
            #pragma unroll
            for (int j = 0; j < 4; j++)
                acc[i][j] = __builtin_amdgcn_mfma_f32_16x16x32_bf16(af[i], bfr[j], acc[i][j], 0, 0, 0);
    }

    // ---- wave-private transpose epilogue ----
    __syncthreads();   // bf16 panels dead; overlay transpose buffers
    float* tw = (float*)smem + w * (32 * 96);   // 12 KB per wave, 48 KB total

    #pragma unroll
    for (int half = 0; half < 2; half++) {
        // scatter exp results into wave-private buffer (2-way banks = free)
        #pragma unroll
        for (int i2 = 0; i2 < 2; i2++) {
            int i = half * 2 + i2;
            #pragma unroll
            for (int j = 0; j < 4; j++) {
                int cl = j * 16 + m;
                float sc = sq[colBase + wc + cl];
                #pragma unroll
                for (int r = 0; r < 4; r++) {
                    int rl = i2 * 16 + quad * 4 + r;   // row within half (0..31)
                    float sr = sq[rowBase + wr + half * 32 + rl];
                    float e = fminf(2.0f * acc[i][j][r] - sr - sc, 0.0f);
                    tw[rl * 96 + (cl ^ ((rl & 7) << 2))] = __expf(e);
                }
            }
        }
        // read back rows (b128, 8 distinct 128B LDS rows/instr) and store
        // full-line-granule dwordx4: 16 lanes x 16B = 256B contiguous/row.
        // DS in-order per wave: no barrier needed, buffer is wave-private.
        #pragma unroll
        for (int k = 0; k < 8; k++) {
            int rw = k * 4 + quad;                     // 0..31
            float4 v = *(const float4*)&tw[rw * 96 + ((m ^ (rw & 7)) << 2)];
            *(float4*)&out[(size_t)(rowBase + wr + half * 32 + rw) * N
                           + colBase + wc + m * 4] = v;
        }
    }
}

extern "C" void kernel_launch(void* const* d_in, const int* in_sizes, int n_in,
                              void* d_out, int out_size, void* d_ws, size_t ws_size,
                              hipStream_t stream) {
    const float* z = (const float*)d_in[0];
    unsigned short* zb = (unsigned short*)d_ws;                       // 2 MB bf16 copy
    float* sqv = (float*)((char*)d_ws + (size_t)N * Dd * sizeof(unsigned short)); // 32 KB norms
    float* out = (float*)d_out;

    prep_kernel<<<N / 4, 256, 0, stream>>>(z, zb, sqv);
    pairsim_kernel<<<dim3(64, 64), 256, 0, stream>>>(zb, sqv, out);
}